// Round 1
// baseline (286.127 us; speedup 1.0000x reference)
//
#include <hip/hip_runtime.h>
#include <hip/hip_bf16.h>
#include <cstdint>

typedef __bf16 bf16_t;
typedef __bf16 bf16x8 __attribute__((ext_vector_type(8)));
typedef float  floatx4 __attribute__((ext_vector_type(4)));

typedef const __attribute__((address_space(1))) unsigned int* gptr_t;
typedef __attribute__((address_space(3))) unsigned int* lptr_t;

static __device__ __forceinline__ void gl2lds16(const bf16_t* g, bf16_t* l) {
  __builtin_amdgcn_global_load_lds((gptr_t)g, (lptr_t)l, 16, 0, 0);
}

#define BAR()   asm volatile("s_barrier" ::: "memory")
#define WLGKM() asm volatile("s_waitcnt lgkmcnt(0)" ::: "memory")

// ---------------------------------------------------------------------------
// ROUND-10: 256x256 8-phase GEMM (T2+T3+T4+T5 per the verified m201 template)
// for the two big GEMMs (QKV projection, scores). NT: C = f(alpha*A*B^T)+bias.
// 8 waves (2M x 4N), per-wave 128x64 output (acc[8][4] floatx4), BK=64 as two
// K=32 halves. LDS 128 KiB = 2 dbuf x {A,B} x {k0,k1} x [256 rows][32 elems].
// Per K-tile, 4 phases: {8,8,4,4} ds_read_b128 + 1 half-tile stage (2x
// global_load_lds dwordx4) + raw s_barrier + lgkmcnt(0) + setprio(1) +
// 16 MFMA + setprio(0) + barrier. Counted s_waitcnt vmcnt(6) ONCE per K-tile
// (3 half-tiles in flight); drain-0 only for the last two K-tiles.
// Stage order/tile: [B-k0, A-k0, B-k1, A-k1]; during tile t phase p we stage
// half s=4t+7+p. Every staged region's last reader is a strictly earlier
// phase of the consuming tile, so the async writes can never beat a read.
// XOR chunk swizzle (involution): LDS slot (row,chunk) holds global chunk
// chunk^((row>>1)&3); staged via pre-swizzled global source (linear LDS dest,
// required by global_load_lds); frag reads apply the same XOR -> measured-0
// bank conflicts (same swizzle as the 128x32 panels of round-9).
// ---------------------------------------------------------------------------
template<int HAS_BIAS, int EXP_COLSUM, int SPLIT3>
__global__ __launch_bounds__(512, 2)
void gemm256(const bf16_t* __restrict__ A, const bf16_t* __restrict__ Bt,
             void* __restrict__ Cv,
             const float* __restrict__ b0, const float* __restrict__ b1,
             const float* __restrict__ b2,
             float* __restrict__ L,
             int M, int N, int K, int ldC, float alpha,
             long sA, long sB, long sC,
             long co0, long co1, long co2,
             int mbShift, int ldTv, long sTv)
{
  __shared__ __align__(16) char smemc[131072];   // 128 KiB

  const int bz = blockIdx.z;
  A  += bz * sA;
  Bt += bz * sB;

  // bijective XCD swizzle (m204): each XCD gets a contiguous run of the
  // original order -> row-panel L2 locality per XCD.
  int bx, by;
  {
    const int gx = gridDim.x, gy = gridDim.y;
    const int nwg = gx * gy;
    int id = blockIdx.x + gx * blockIdx.y;
    const int q = nwg >> 3, r = nwg & 7;
    const int xcd = id & 7, o = id >> 3;
    id = (xcd < r ? xcd * (q + 1) : r * (q + 1) + (xcd - r) * q) + o;
    bx = id % gx;
    by = id / gx;
  }

  const int gn0 = bx * 256;
  const int m0  = by * 256;
  const int tid  = threadIdx.x;
  const int lane = tid & 63;
  const int wave = tid >> 6;
  const int wm   = wave >> 2;      // 0..1  (M half)
  const int wn   = wave & 3;       // 0..3  (N quarter)
  const int lm   = lane & 15;
  const int quad = lane >> 4;

  int n0 = gn0, which = 0;
  bf16_t* Cb = (bf16_t*)Cv;
  const float* bias = b0;
  if (SPLIT3) {
    which = gn0 >> 10;
    n0 = gn0 & 1023;
    Cb += (which == 0) ? co0 : (which == 1) ? co1 : co2;
    bias = (which == 0) ? b0 : (which == 1) ? b1 : b2;
  }

  // staging: thread t -> LDS row tid>>2 (+128*issue), chunk tid&3 (linear
  // dest); global source chunk pre-swizzled: (tid&3) ^ ((tid>>3)&3) == XOR of
  // LDS chunk with row bits 1-2.
  const int srow = tid >> 2;                        // 0..127
  const int scol = ((tid ^ (tid >> 3)) & 3) * 8;    // pre-swizzled col (elems)
  const bf16_t* pA = A  + (long)(m0  + srow) * K + scol;
  const bf16_t* pB = Bt + (long)(gn0 + srow) * K + scol;

  const int nt = K >> 6;            // K-tiles of 64

  auto STAGE = [&](int s) {
    if (s >= 4 * nt) return;
    const int ts  = s >> 2;
    const int h   = s & 3;          // 0=B-k0 1=A-k0 2=B-k1 3=A-k1
    const int isA = h & 1;
    const int kh  = h >> 1;
    const bf16_t* gp = (isA ? pA : pB) + ts * 64 + kh * 32;
    char* lp = smemc + (ts & 1) * 65536 + (isA ? 0 : 32768) + kh * 16384
             + tid * 16;
    gl2lds16(gp,                (bf16_t*)lp);
    gl2lds16(gp + (long)128 * K, (bf16_t*)(lp + 8192));
  };

  // fragment-read byte offsets (chunk XOR-swizzled; rows are 64 B)
  const int csz  = ((quad ^ (lm >> 1)) & 3) * 16;
  const int aoff = (wm * 128 + lm) * 64 + csz;
  const int boff = (wn * 64  + lm) * 64 + csz;
  auto LDA = [&](int buf, int ks, int f) {
    return *(const bf16x8*)(smemc + buf * 65536 + ks * 16384 + aoff + f * 1024);
  };
  auto LDB = [&](int buf, int ks, int j) {
    return *(const bf16x8*)(smemc + buf * 65536 + 32768 + ks * 16384 + boff
                            + j * 1024);
  };

  floatx4 acc[8][4];
#pragma unroll
  for (int f = 0; f < 8; ++f)
#pragma unroll
    for (int j = 0; j < 4; ++j)
      acc[f][j] = (floatx4)(0.f);

  // prologue: tile0 complete + 3 halves of tile1 in flight
#pragma unroll
  for (int s = 0; s < 7; ++s) STAGE(s);
  asm volatile("s_waitcnt vmcnt(6)" ::: "memory");
  BAR();

  for (int t = 0; t < nt; ++t) {
    const int buf = t & 1;
    bf16x8 a[4], b0r[4], b1r[4];

    // ---- phase 0: read B ks0 (4) + A f0-3 ks0 (4); stage A-k1(t+1)
#pragma unroll
    for (int j = 0; j < 4; ++j) b0r[j] = LDB(buf, 0, j);
#pragma unroll
    for (int f = 0; f < 4; ++f) a[f] = LDA(buf, 0, f);
    STAGE(4 * t + 7);
    BAR(); WLGKM();
    __builtin_amdgcn_s_setprio(1);
#pragma unroll
    for (int f = 0; f < 4; ++f)
#pragma unroll
      for (int j = 0; j < 4; ++j)
        acc[f][j] = __builtin_amdgcn_mfma_f32_16x16x32_bf16(a[f], b0r[j],
                                                            acc[f][j], 0, 0, 0);
    __builtin_amdgcn_s_setprio(0);
    BAR();

    // ---- phase 1: read B ks1 (4) + A f4-7 ks0 (4); stage B-k0(t+2)
#pragma unroll
    for (int j = 0; j < 4; ++j) b1r[j] = LDB(buf, 1, j);
#pragma unroll
    for (int f = 0; f < 4; ++f) a[f] = LDA(buf, 0, 4 + f);
    STAGE(4 * t + 8);
    BAR(); WLGKM();
    __builtin_amdgcn_s_setprio(1);
#pragma unroll
    for (int f = 0; f < 4; ++f)
#pragma unroll
      for (int j = 0; j < 4; ++j)
        acc[4 + f][j] = __builtin_amdgcn_mfma_f32_16x16x32_bf16(a[f], b0r[j],
                                                                acc[4 + f][j], 0, 0, 0);
    __builtin_amdgcn_s_setprio(0);
    BAR();

    // ---- phase 2: read A f0-3 ks1 (4); stage A-k0(t+2)
#pragma unroll
    for (int f = 0; f < 4; ++f) a[f] = LDA(buf, 1, f);
    STAGE(4 * t + 9);
    BAR(); WLGKM();
    __builtin_amdgcn_s_setprio(1);
#pragma unroll
    for (int f = 0; f < 4; ++f)
#pragma unroll
      for (int j = 0; j < 4; ++j)
        acc[f][j] = __builtin_amdgcn_mfma_f32_16x16x32_bf16(a[f], b1r[j],
                                                            acc[f][j], 0, 0, 0);
    __builtin_amdgcn_s_setprio(0);
    BAR();

    // ---- phase 3: read A f4-7 ks1 (4); stage B-k1(t+2); counted vmcnt
#pragma unroll
    for (int f = 0; f < 4; ++f) a[f] = LDA(buf, 1, 4 + f);
    STAGE(4 * t + 10);
    BAR(); WLGKM();
    __builtin_amdgcn_s_setprio(1);
#pragma unroll
    for (int f = 0; f < 4; ++f)
#pragma unroll
      for (int j = 0; j < 4; ++j)
        acc[4 + f][j] = __builtin_amdgcn_mfma_f32_16x16x32_bf16(a[f], b1r[j],
                                                                acc[4 + f][j], 0, 0, 0);
    __builtin_amdgcn_s_setprio(0);
    if (t < nt - 2) { asm volatile("s_waitcnt vmcnt(6)" ::: "memory"); }
    else            { asm volatile("s_waitcnt vmcnt(0)" ::: "memory"); }
    BAR();
  }

  // ---------------- epilogue (C/D layout: col=lm, row=quad*4+r; m89/m91) ----
  const int r8 = lane >> 3;
  const int c8 = lane & 7;

  if (SPLIT3 && which == 2) {
    // transposed store: Vt[b][d][s]
    bf16_t* myT = (bf16_t*)(smemc + wave * 4608);   // [16][144]
    const int b  = m0 >> mbShift;
    const int s0 = m0 & ((1 << mbShift) - 1);
#pragma unroll
    for (int j = 0; j < 4; ++j) {
      const float bv = HAS_BIAS ? bias[n0 + wn * 64 + j * 16 + lm] : 0.f;
#pragma unroll
      for (int f = 0; f < 8; ++f)
#pragma unroll
        for (int r = 0; r < 4; ++r)
          myT[lm * 144 + f * 16 + quad * 4 + r] = (bf16_t)(acc[f][j][r] + bv);
      // per-wave region + in-order DS pipe: no barrier needed
#pragma unroll
      for (int t2 = 0; t2 < 4; ++t2) {
        const int dr = (t2 & 1) * 8 + r8;
        const int ck = (t2 >> 1) * 8 + c8;
        const bf16x8 vv = *(const bf16x8*)&myT[dr * 144 + ck * 8];
        *(bf16x8*)&Cb[(long)b * sTv + (long)(n0 + wn * 64 + j * 16 + dr) * ldTv
                      + s0 + wm * 128 + ck * 8] = vv;
      }
    }
  } else {
    bf16_t* myEp = (bf16_t*)(smemc + wave * 2176);  // [16][68]
    float csum[4] = {0.f, 0.f, 0.f, 0.f};
    float bv[4];
#pragma unroll
    for (int j = 0; j < 4; ++j)
      bv[j] = HAS_BIAS ? bias[n0 + wn * 64 + j * 16 + lm] : 0.f;
#pragma unroll
    for (int f = 0; f < 8; ++f) {
#pragma unroll
      for (int j = 0; j < 4; ++j)
#pragma unroll
        for (int r = 0; r < 4; ++r) {
          float v = acc[f][j][r];
          if (EXP_COLSUM) { v = __expf(alpha * v); csum[j] += v; }
          v += bv[j];
          myEp[(quad * 4 + r) * 68 + j * 16 + lm] = (bf16_t)v;
        }
#pragma unroll
      for (int t2 = 0; t2 < 2; ++t2) {
        const int row = t2 * 8 + r8;
        const bf16x8 vv = *(const bf16x8*)&myEp[row * 68 + c8 * 8];
        *(bf16x8*)&Cb[bz * sC + (long)(m0 + wm * 128 + f * 16 + row) * ldC
                      + n0 + wn * 64 + c8 * 8] = vv;
      }
    }
    if (EXP_COLSUM) {
#pragma unroll
      for (int j = 0; j < 4; ++j) {
        float v = csum[j];
        v += __shfl_xor(v, 16);
        v += __shfl_xor(v, 32);
        if (quad == 0)
          atomicAdd(&L[bz * N + gn0 + wn * 64 + j * 16 + lm], v);
      }
    }
  }
}

// ---------------------------------------------------------------------------
// Round-9 128x128 kernel, kept for the two small GEMMs (ctx: 512 blocks,
// out: 512 blocks — 256^2 tiles would leave half the CUs idle there).
// ---------------------------------------------------------------------------
template<int OUT_BF16, int HAS_BIAS, int EXP_COLSUM, int SPLIT3>
__global__ __launch_bounds__(256, 4)
void gemm_nt(const bf16_t* __restrict__ A, const bf16_t* __restrict__ Bt,
             void* __restrict__ Cv,
             const float* __restrict__ b0, const float* __restrict__ b1,
             const float* __restrict__ b2,
             float* __restrict__ L,
             int M, int N, int K, int ldC, float alpha,
             long sA, long sB, long sC,
             long co0, long co1, long co2,
             int mbShift, int ldTv, long sTv)
{
  __shared__ __align__(16) bf16_t smem[4 * 128 * 32];  // 32 KB
  bf16_t* As0 = smem;
  bf16_t* Bs0 = smem + 4096;
  bf16_t* As1 = smem + 8192;
  bf16_t* Bs1 = smem + 12288;

  const int bz = blockIdx.z;
  A  += bz * sA;
  Bt += bz * sB;

  // XCD-aware swizzle v2
  int bx = blockIdx.x, by = blockIdx.y;
  {
    const int gx = gridDim.x, gy = gridDim.y;
    const int nb = gx * gy;
    if (((nb & 7) == 0) && ((gx & 3) == 0) && ((gy & 7) == 0)) {
      const int id   = bx + gx * by;
      const int xcd  = id & 7;
      const int o    = id >> 3;
      const int rows = gy >> 3;
      const int pw   = rows << 2;
      const int p    = o / pw;
      const int r    = o - p * pw;
      by = xcd * rows + (r >> 2);
      bx = (p << 2) + (r & 3);
    }
  }

  const int gn0 = bx * 128;
  const int m0  = by * 128;
  const int tid  = threadIdx.x;
  const int lane = tid & 63;
  const int wave = tid >> 6;
  const int wm   = (wave >> 1) * 64;
  const int wn   = (wave & 1) * 64;
  const int lm   = lane & 15;
  const int quad = lane >> 4;

  int n0 = gn0;
  int which = 0;
  bf16_t* Cb = (bf16_t*)Cv;
  float*  Cf = (float*)Cv;
  const float* bias = b0;
  if (SPLIT3) {
    which = gn0 >> 10;
    n0 = gn0 & 1023;
    Cb += (which == 0) ? co0 : (which == 1) ? co1 : co2;
    bias = (which == 0) ? b0 : (which == 1) ? b1 : b2;
  }

  const int srow   = lane >> 2;
  const int schunk = (lane & 3) * 8;
  const int gchunk = ((lane & 3) ^ ((srow >> 1) & 3)) * 8;
  const int fswz   = ((lm >> 1) & 3) * 8;

  floatx4 acc[4][4];
#pragma unroll
  for (int i = 0; i < 4; ++i)
#pragma unroll
    for (int j = 0; j < 4; ++j)
      acc[i][j] = (floatx4)(0.f);

  for (int kk = 0; kk < K; kk += 64) {
    __syncthreads();
#pragma unroll
    for (int t = 0; t < 2; ++t) {
      const int r = wave * 32 + t * 16 + srow;
      const long ar = (long)(m0  + r) * K + kk + gchunk;
      const long br = (long)(gn0 + r) * K + kk + gchunk;
      gl2lds16(A  + ar,      &As0[r * 32 + schunk]);
      gl2lds16(A  + ar + 32, &As1[r * 32 + schunk]);
      gl2lds16(Bt + br,      &Bs0[r * 32 + schunk]);
      gl2lds16(Bt + br + 32, &Bs1[r * 32 + schunk]);
    }
    __syncthreads();

    {
      bf16x8 af[4], bfr[4];
#pragma unroll
      for (int i = 0; i < 4; ++i)
        af[i] = *(const bf16x8*)&As0[(wm + i * 16 + lm) * 32 + ((quad * 8) ^ fswz)];
#pragma unroll
      for (int j = 0; j < 4; ++j)
        bfr[j] = *(const bf16x8*)&Bs0[(wn + j * 16 + lm) * 32 + ((quad * 8) ^ fswz)];
#pragma unroll
      for (int i = 0; i < 4; ++i)
#pragma unroll
        for (int j = 0; j < 4; ++j)
          acc[i][j] = __builtin_amdgcn_mfma_f32_16x16x32_bf16(af[i], bfr[j],
                                                              acc[i][j], 0, 0, 0);
    }
    {
      bf16x8 af[4], bfr[4];
#pragma unroll
      for (int i = 0; i < 4; ++i)
        af[i] = *(const bf16x8*)&As1[(wm + i * 16 + lm) * 32 + ((quad * 8) ^ fswz)];
#pragma unroll
      for (int j = 0; j < 4; ++j)
        bfr[j] = *(const bf16x8*)&Bs1[(wn + j * 16 + lm) * 32 + ((quad * 8) ^ fswz)];
#pragma unroll
      for (int i = 0; i < 4; ++i)
#pragma unroll
        for (int j = 0; j < 4; ++j)
          acc[i][j] = __builtin_amdgcn_mfma_f32_16x16x32_bf16(af[i], bfr[j],
                                                              acc[i][j], 0, 0, 0);
    }
  }

  if (SPLIT3 && which == 2) {
    __syncthreads();
    bf16_t* myT = smem + wave * (16 * 68);
    const int b  = m0 >> mbShift;
    const int s0 = m0 & ((1 << mbShift) - 1);
    const int r8 = lane >> 3;
    const int c8 = lane & 7;
#pragma unroll
    for (int j = 0; j < 4; ++j) {
      const float bv = HAS_BIAS ? bias[n0 + wn + j * 16 + lm] : 0.f;
#pragma unroll
      for (int i = 0; i < 4; ++i)
#pragma unroll
        for (int r = 0; r < 4; ++r)
          myT[lm * 68 + i * 16 + quad * 4 + r] = (bf16_t)(acc[i][j][r] + bv);
#pragma unroll
      for (int t = 0; t < 2; ++t) {
        const int nr = t * 8 + r8;
        const bf16x8 vv = *(const bf16x8*)&myT[nr * 68 + c8 * 8];
        *(bf16x8*)&Cb[(long)b * sTv + (long)(n0 + wn + j * 16 + nr) * ldTv
                      + s0 + wm + c8 * 8] = vv;
      }
    }
  } else if (OUT_BF16) {
    __syncthreads();
    bf16_t* myEp = smem + wave * (16 * 68);
    const int r8 = lane >> 3;
    const int c8 = lane & 7;
    float cs[4] = {0.f, 0.f, 0.f, 0.f};
#pragma unroll
    for (int i = 0; i < 4; ++i) {
#pragma unroll
      for (int j = 0; j < 4; ++j) {
        const float bv = HAS_BIAS ? bias[n0 + wn + j * 16 + lm] : 0.f;
#pragma unroll
        for (int r = 0; r < 4; ++r) {
          float v = alpha * acc[i][j][r];
          if (EXP_COLSUM) { v = __expf(v); cs[j] += v; }
          v += bv;
          myEp[(quad * 4 + r) * 68 + j * 16 + lm] = (bf16_t)v;
        }
      }
#pragma unroll
      for (int t = 0; t < 2; ++t) {
        const int row = t * 8 + r8;
        const bf16x8 vv = *(const bf16x8*)&myEp[row * 68 + c8 * 8];
        *(bf16x8*)&Cb[bz * sC + (long)(m0 + wm + i * 16 + row) * ldC
                      + n0 + wn + c8 * 8] = vv;
      }
    }
    if (EXP_COLSUM) {
#pragma unroll
      for (int j = 0; j < 4; ++j) {
        float v = cs[j];
        v += __shfl_xor(v, 16);
        v += __shfl_xor(v, 32);
        if (quad == 0)
          atomicAdd(&L[bz * N + gn0 + wn + j * 16 + lm], v);
      }
    }
  } else {
#pragma unroll
    for (int j = 0; j < 4; ++j) {
      const int cn = n0 + wn + j * 16 + lm;
      const float bv = HAS_BIAS ? bias[n0 + wn + j * 16 + lm] : 0.f;
#pragma unroll
      for (int i = 0; i < 4; ++i) {
        const int rbase = m0 + wm + i * 16 + quad * 4;
#pragma unroll
        for (int r = 0; r < 4; ++r)
          Cf[bz * sC + (long)(rbase + r) * ldC + cn] = alpha * acc[i][j][r] + bv;
      }
    }
  }
}

// ---------------------------------------------------------------------------
__global__ __launch_bounds__(256)
void prep(const float* __restrict__ x, bf16_t* __restrict__ Xb,
          const float* __restrict__ w0, const float* __restrict__ w1,
          const float* __restrict__ w2, const float* __restrict__ w3,
          bf16_t* __restrict__ outQKV, bf16_t* __restrict__ outO)
{
  __shared__ float tile[32][33];
  const int id = blockIdx.x;
  if (id < 8192) {
    const long i = ((long)id * 256 + threadIdx.x) * 4;
    const float4 v = *(const float4*)(x + i);
    struct alignas(8) B4 { bf16_t a, b, c, d; };
    B4 o; o.a = (bf16_t)v.x; o.b = (bf16_t)v.y; o.c = (bf16_t)v.z; o.d = (bf16_t)v.w;
    *(B4*)(Xb + i) = o;
  } else {
    const int t = id - 8192;
    const int z = t >> 10;
    const int bx = t & 31, by = (t >> 5) & 31;
    const float* in = (z == 0) ? w0 : (z == 1) ? w1 : (z == 2) ? w2 : w3;
    bf16_t* out = (z < 3) ? outQKV + (long)z * 1024 * 1024 : outO;
    const int c0 = bx * 32, r0 = by * 32;
    const int tx = threadIdx.x & 31;
    const int ty = threadIdx.x >> 5;
#pragma unroll
    for (int i = 0; i < 32; i += 8)
      tile[ty + i][tx] = in[(long)(r0 + ty + i) * 1024 + (c0 + tx)];
    __syncthreads();
#pragma unroll
    for (int i = 0; i < 32; i += 8)
      out[(long)(c0 + ty + i) * 1024 + (r0 + tx)] = (bf16_t)tile[tx][ty + i];
  }
}

// Vt[b][d][s] *= 1/L[b][s]
__global__ __launch_bounds__(256)
void scale_vt(bf16_t* __restrict__ Vt, const float* __restrict__ L, int S)
{
  const long base = ((long)blockIdx.x * blockDim.x + threadIdx.x) * 8;
  const int b  = (int)(base >> 21);
  const int s0 = (int)(base & (long)(S - 1));
  const float* Lb = L + b * S + s0;
  bf16x8 v = *(const bf16x8*)(Vt + base);
#pragma unroll
  for (int j = 0; j < 8; ++j)
    v[j] = (bf16_t)((float)v[j] / Lb[j]);
  *(bf16x8*)(Vt + base) = v;
}

// ---------------------------------------------------------------------------
extern "C" void kernel_launch(void* const* d_in, const int* in_sizes, int n_in,
                              void* d_out, int out_size, void* d_ws, size_t ws_size,
                              hipStream_t stream)
{
  const int Bz = 4, S = 2048, F = 1024, DK = 1024;
  const int M = Bz * S;

  const float* x  = (const float*)d_in[0];
  const float* Wq = (const float*)d_in[1];
  const float* bq = (const float*)d_in[2];
  const float* Wk = (const float*)d_in[3];
  const float* bk = (const float*)d_in[4];
  const float* Wv = (const float*)d_in[5];
  const float* bv = (const float*)d_in[6];
  const float* Wo = (const float*)d_in[7];
  const float* bo = (const float*)d_in[8];

  char* ws = (char*)d_ws;
  const size_t MB = 1ull << 20;
  bf16_t* Xb   = (bf16_t*)(ws + 0);
  bf16_t* Sc   = (bf16_t*)(ws + 0);
  bf16_t* Q    = (bf16_t*)(ws + 32 * MB);
  bf16_t* Ctx  = (bf16_t*)(ws + 32 * MB);
  bf16_t* Kb   = (bf16_t*)(ws + 48 * MB);
  bf16_t* Vt   = (bf16_t*)(ws + 64 * MB);
  bf16_t* WcatT= (bf16_t*)(ws + 80 * MB);
  float*  L    = (float*)(ws + 80 * MB);
  bf16_t* WoT  = (bf16_t*)(ws + 86 * MB);

  const long coQ = 16 * MB;
  const long coK = 24 * MB;
  const long coV = 32 * MB;

  prep<<<12288, 256, 0, stream>>>(x, Xb, Wq, Wk, Wv, Wo, WcatT, WoT);

  // merged Q/K/V projection (256^2 8-phase); V chunk stored transposed
  gemm256<1, 0, 1><<<dim3(3 * DK / 256, M / 256, 1), 512, 0, stream>>>(
      Xb, WcatT, (void*)ws, bq, bk, bv, nullptr, M, 3 * DK, F, DK, 1.f,
      0, 0, 0, coQ, coK, coV, 11, S, (long)DK * S);

  // P = exp(Q.K/sqrt(dk)); column sums -> L (256^2 8-phase, fused atomics)
  hipMemsetAsync(L, 0, (size_t)Bz * S * sizeof(float), stream);
  gemm256<0, 1, 0><<<dim3(S / 256, S / 256, Bz), 512, 0, stream>>>(
      Q, Kb, Sc, nullptr, nullptr, nullptr, L, S, S, DK, S, 0.03125f,
      (long)S * DK, (long)S * DK, (long)S * S, 0, 0, 0, 0, 0, 0);

  scale_vt<<<((long)Bz * DK * S / 8) / 256, 256, 0, stream>>>(Vt, L, S);

  // ctx = P @ (V/L)  (128^2 kernel: 512 blocks keeps the machine full)
  gemm_nt<1, 0, 0, 0><<<dim3(DK / 128, S / 128, Bz), 256, 0, stream>>>(
      Sc, Vt, Ctx, nullptr, nullptr, nullptr, nullptr, S, DK, S, DK, 1.f,
      (long)S * S, (long)S * DK, (long)S * DK, 0, 0, 0, 0, 0, 0);

  // out = ctx @ Wo + bo (fp32)
  gemm_nt<0, 1, 0, 0><<<dim3(F / 128, M / 128, 1), 256, 0, stream>>>(
      Ctx, WoT, d_out, bo, nullptr, nullptr, nullptr, M, F, DK, F, 1.f,
      0, 0, 0, 0, 0, 0, 0, 0, 0);
}